// Round 3
// baseline (2983.090 us; speedup 1.0000x reference)
//
#include <hip/hip_runtime.h>

#define N_NODES 25600
#define N_EDGES 409600
#define BGR 128
#define EFE 1024
#define DIM 128
#define NLAYERS 8
#define KPOOL 32
#define NPG 200

typedef unsigned short ushort_t;

__device__ __forceinline__ ushort_t f2b(float f) {
    unsigned int u = __float_as_uint(f);
    unsigned int r = (u + 0x7fffu + ((u >> 16) & 1u)) >> 16;
    return (ushort_t)r;
}

// pack 4 floats -> 4 bf16 in uint2
__device__ __forceinline__ uint2 pack4(float4 v) {
    uint2 p;
    p.x = (unsigned int)f2b(v.x) | ((unsigned int)f2b(v.y) << 16);
    p.y = (unsigned int)f2b(v.z) | ((unsigned int)f2b(v.w) << 16);
    return p;
}

// ---------------- zero deg (replaces hipMemsetAsync for capture safety) ----------------
__global__ void zero_deg(int* __restrict__ deg, int n) {
    int i = blockIdx.x * 256 + threadIdx.x;
    if (i < n) deg[i] = 0;
}

// ---------------- CSR build ----------------
__global__ void count_deg(const int* __restrict__ dst, int* __restrict__ deg, int n) {
    int i = blockIdx.x * 256 + threadIdx.x;
    if (i < n) atomicAdd(&deg[dst[i]], 1);
}

__global__ __launch_bounds__(1024) void scan_kernel(const int* __restrict__ deg,
                                                    int* __restrict__ off,
                                                    int* __restrict__ cursor, int n) {
    __shared__ int buf[1024];
    __shared__ int carry;
    int t = threadIdx.x;
    if (t == 0) carry = 0;
    __syncthreads();
    for (int base = 0; base < n; base += 1024) {
        int v = (base + t < n) ? deg[base + t] : 0;
        buf[t] = v;
        __syncthreads();
        for (int s = 1; s < 1024; s <<= 1) {
            int x = (t >= s) ? buf[t - s] : 0;
            __syncthreads();
            buf[t] += x;
            __syncthreads();
        }
        int excl = buf[t] - v;
        if (base + t < n) { off[base + t] = carry + excl; cursor[base + t] = carry + excl; }
        __syncthreads();
        if (t == 1023) carry += buf[1023];
        __syncthreads();
    }
    if (t == 0) off[n] = carry;
}

__global__ void scatter_csr(const int* __restrict__ dst, int* __restrict__ cursor,
                            int* __restrict__ csr, int n) {
    int i = blockIdx.x * 256 + threadIdx.x;
    if (i < n) {
        int p = atomicAdd(&cursor[dst[i]], 1);
        csr[p] = i;
    }
}

// ---------------- init ----------------
__global__ void init_h(const int* __restrict__ tok, const float* __restrict__ emb,
                       float* __restrict__ h) {
    int i = blockIdx.x * 256 + threadIdx.x;  // N*D total
    int r = i >> 7, d = i & 127;
    float v = emb[tok[r] * DIM + d];
    h[i] = fmaxf(v, 0.f);
}

// eftab[t][d] = sum_k e_token_emb[t][k] * W_fij0[k][d]   (100 x 128, fp32)
__global__ __launch_bounds__(128) void eftab_kernel(const float* __restrict__ etab,
                                                    const float* __restrict__ W,
                                                    float* __restrict__ out) {
    int r = blockIdx.x, d = threadIdx.x;
    float acc = 0.f;
    for (int k = 0; k < DIM; k++)
        acc += etab[r * DIM + k] * W[k * DIM + d];
    out[r * DIM + d] = acc;
}

// ---------------- node GEMMs: C = A(fp32 Nx128) @ W(fp32->bf16 128x128) ----------------
__global__ __launch_bounds__(256) void node_gemm3(
    const float* __restrict__ A,
    const float* __restrict__ W0, const float* __restrict__ W1,
    const float* __restrict__ W2,
    float* __restrict__ C0, float* __restrict__ C1, float* __restrict__ C2) {
    __shared__ float As[64 * 128];   // 32 KB
    __shared__ uint2 Ws4[128 * 32];  // 32 KB (bf16 x4 per uint2)
    int tid = threadIdx.x;
    size_t row0 = (size_t)blockIdx.x * 64;
    const float4* Ag = (const float4*)(A + row0 * DIM);
    for (int f = tid; f < 64 * 32; f += 256) ((float4*)As)[f] = Ag[f];
    int cq = tid & 31, r0 = (tid >> 5) * 8;
    const float* Wlist[3] = {W0, W1, W2};
    float* Clist[3] = {C0, C1, C2};
    for (int m = 0; m < 3; m++) {
        __syncthreads();
        const float4* Wg = (const float4*)Wlist[m];
        for (int i = tid; i < 128 * 32; i += 256) Ws4[i] = pack4(Wg[i]);
        __syncthreads();
        float acc[8][4] = {};
        for (int k = 0; k < 128; k++) {
            uint2 wp = Ws4[k * 32 + cq];
            float w0 = __uint_as_float(wp.x << 16);
            float w1 = __uint_as_float(wp.x & 0xffff0000u);
            float w2 = __uint_as_float(wp.y << 16);
            float w3 = __uint_as_float(wp.y & 0xffff0000u);
#pragma unroll
            for (int i = 0; i < 8; i++) {
                float a = As[(r0 + i) * 128 + k];
                acc[i][0] += a * w0; acc[i][1] += a * w1;
                acc[i][2] += a * w2; acc[i][3] += a * w3;
            }
        }
        float* Cp = Clist[m];
#pragma unroll
        for (int i = 0; i < 8; i++) {
            *(float4*)&Cp[(row0 + r0 + i) * DIM + cq * 4] =
                make_float4(acc[i][0], acc[i][1], acc[i][2], acc[i][3]);
        }
    }
}

// single-W with bias + relu (final Wf)
__global__ __launch_bounds__(256) void node_gemm1(
    const float* __restrict__ A, const float* __restrict__ W,
    const float* __restrict__ bias, float* __restrict__ C) {
    __shared__ float As[64 * 128];
    __shared__ uint2 Ws4[128 * 32];
    int tid = threadIdx.x;
    size_t row0 = (size_t)blockIdx.x * 64;
    const float4* Ag = (const float4*)(A + row0 * DIM);
    for (int f = tid; f < 64 * 32; f += 256) ((float4*)As)[f] = Ag[f];
    const float4* Wg = (const float4*)W;
    for (int i = tid; i < 128 * 32; i += 256) Ws4[i] = pack4(Wg[i]);
    __syncthreads();
    int cq = tid & 31, r0 = (tid >> 5) * 8, c0 = cq * 4;
    float acc[8][4] = {};
    for (int k = 0; k < 128; k++) {
        uint2 wp = Ws4[k * 32 + cq];
        float w0 = __uint_as_float(wp.x << 16);
        float w1 = __uint_as_float(wp.x & 0xffff0000u);
        float w2 = __uint_as_float(wp.y << 16);
        float w3 = __uint_as_float(wp.y & 0xffff0000u);
#pragma unroll
        for (int i = 0; i < 8; i++) {
            float a = As[(r0 + i) * 128 + k];
            acc[i][0] += a * w0; acc[i][1] += a * w1;
            acc[i][2] += a * w2; acc[i][3] += a * w3;
        }
    }
    float b0 = bias[c0], b1 = bias[c0 + 1], b2v = bias[c0 + 2], b3v = bias[c0 + 3];
#pragma unroll
    for (int i = 0; i < 8; i++) {
        *(float4*)&C[(row0 + r0 + i) * DIM + c0] =
            make_float4(fmaxf(acc[i][0] + b0, 0.f), fmaxf(acc[i][1] + b1, 0.f),
                        fmaxf(acc[i][2] + b2v, 0.f), fmaxf(acc[i][3] + b3v, 0.f));
    }
}

// ---------------- fused edge GEMM (layers 1..7), in-place e ----------------
__global__ __launch_bounds__(256) void edge_gemm(
    float* __restrict__ e, const float* __restrict__ fni, const float* __restrict__ fnj,
    const int* __restrict__ src, const int* __restrict__ dst,
    const float* __restrict__ Wfij, const float* __restrict__ attn,
    const float* __restrict__ bias, float* __restrict__ score) {
    __shared__ float As[64 * 128];
    __shared__ uint2 Ws4[128 * 32];
    int tid = threadIdx.x;
    size_t e0 = (size_t)blockIdx.x * 64;
    const float4* Ag = (const float4*)(e + e0 * DIM);
    for (int f = tid; f < 64 * 32; f += 256) ((float4*)As)[f] = Ag[f];
    const float4* Wg = (const float4*)Wfij;
    for (int i = tid; i < 128 * 32; i += 256) Ws4[i] = pack4(Wg[i]);
    __syncthreads();
    int cq = tid & 31, r0 = (tid >> 5) * 8, c0 = cq * 4;
    float acc[8][4] = {};
    for (int k = 0; k < 128; k++) {
        uint2 wp = Ws4[k * 32 + cq];
        float w0 = __uint_as_float(wp.x << 16);
        float w1 = __uint_as_float(wp.x & 0xffff0000u);
        float w2 = __uint_as_float(wp.y << 16);
        float w3 = __uint_as_float(wp.y & 0xffff0000u);
#pragma unroll
        for (int i = 0; i < 8; i++) {
            float a = As[(r0 + i) * 128 + k];
            acc[i][0] += a * w0; acc[i][1] += a * w1;
            acc[i][2] += a * w2; acc[i][3] += a * w3;
        }
    }
    float b0 = bias[c0], b1 = bias[c0 + 1], b2v = bias[c0 + 2], b3v = bias[c0 + 3];
    float a0 = attn[c0], a1 = attn[c0 + 1], a2 = attn[c0 + 2], a3 = attn[c0 + 3];
#pragma unroll
    for (int i = 0; i < 8; i++) {
        size_t eid = e0 + r0 + i;
        int sv = src[eid], dv = dst[eid];
        float4 ni = *(const float4*)&fni[(size_t)sv * DIM + c0];
        float4 nj = *(const float4*)&fnj[(size_t)dv * DIM + c0];
        float v0 = acc[i][0] + ni.x + nj.x + b0;
        float v1 = acc[i][1] + ni.y + nj.y + b1;
        float v2 = acc[i][2] + ni.z + nj.z + b2v;
        float v3 = acc[i][3] + ni.w + nj.w + b3v;
        v0 = v0 > 0.f ? v0 : 0.01f * v0;
        v1 = v1 > 0.f ? v1 : 0.01f * v1;
        v2 = v2 > 0.f ? v2 : 0.01f * v2;
        v3 = v3 > 0.f ? v3 : 0.01f * v3;
        *(float4*)&e[eid * DIM + c0] = make_float4(v0, v1, v2, v3);
        float p = v0 * a0 + v1 * a1 + v2 * a2 + v3 * a3;
#pragma unroll
        for (int o = 1; o < 32; o <<= 1) p += __shfl_xor(p, o);
        if (cq == 0) score[eid] = p;
    }
}

// ---------------- layer-0 edge kernel: ef row comes from 100-row table ----------------
__global__ __launch_bounds__(256) void edge0(
    const int* __restrict__ tokens_e, const float* __restrict__ eftab,
    const float* __restrict__ fni, const float* __restrict__ fnj,
    const int* __restrict__ src, const int* __restrict__ dst,
    const float* __restrict__ attn, const float* __restrict__ bias,
    float* __restrict__ e, float* __restrict__ score) {
    unsigned int gid = blockIdx.x * 256 + threadIdx.x;  // E*32 threads
    unsigned int eid = gid >> 5;
    int cq = gid & 31, c0 = cq * 4;
    int tok = tokens_e[eid];
    int sv = src[eid], dv = dst[eid];
    float4 t = *(const float4*)&eftab[tok * DIM + c0];
    float4 ni = *(const float4*)&fni[(size_t)sv * DIM + c0];
    float4 nj = *(const float4*)&fnj[(size_t)dv * DIM + c0];
    float v0 = t.x + ni.x + nj.x + bias[c0];
    float v1 = t.y + ni.y + nj.y + bias[c0 + 1];
    float v2 = t.z + ni.z + nj.z + bias[c0 + 2];
    float v3 = t.w + ni.w + nj.w + bias[c0 + 3];
    v0 = v0 > 0.f ? v0 : 0.01f * v0;
    v1 = v1 > 0.f ? v1 : 0.01f * v1;
    v2 = v2 > 0.f ? v2 : 0.01f * v2;
    v3 = v3 > 0.f ? v3 : 0.01f * v3;
    *(float4*)&e[(size_t)eid * DIM + c0] = make_float4(v0, v1, v2, v3);
    float p = v0 * attn[c0] + v1 * attn[c0 + 1] + v2 * attn[c0 + 2] + v3 * attn[c0 + 3];
#pragma unroll
    for (int o = 1; o < 32; o <<= 1) p += __shfl_xor(p, o);
    if (cq == 0) score[eid] = p;
}

// ---------------- per-node softmax + weighted aggregation ----------------
__global__ __launch_bounds__(128) void agg_kernel(
    const int* __restrict__ off, const int* __restrict__ csr, const int* __restrict__ src,
    const float* __restrict__ score, const float* __restrict__ hs, float* __restrict__ h) {
    int n = blockIdx.x, t = threadIdx.x;
    int b0 = off[n], b1 = off[n + 1];
    int deg = b1 - b0;
    __shared__ float red[128];
    __shared__ float wgt[128];
    __shared__ int sidx[128];
    float m = -1e30f;
    for (int j = t; j < deg; j += 128) m = fmaxf(m, score[csr[b0 + j]]);
    red[t] = m;
    __syncthreads();
    for (int s = 64; s > 0; s >>= 1) { if (t < s) red[t] = fmaxf(red[t], red[t + s]); __syncthreads(); }
    m = red[0];
    __syncthreads();
    float se = 0.f;
    for (int j = t; j < deg; j += 128) se += __expf(score[csr[b0 + j]] - m);
    red[t] = se;
    __syncthreads();
    for (int s = 64; s > 0; s >>= 1) { if (t < s) red[t] += red[t + s]; __syncthreads(); }
    float inv = (deg > 0) ? 1.f / red[0] : 0.f;
    __syncthreads();
    float acc = 0.f;
    for (int base = 0; base < deg; base += 128) {
        int c = min(128, deg - base);
        if (t < c) {
            int eid = csr[b0 + base + t];
            wgt[t] = __expf(score[eid] - m) * inv;
            sidx[t] = src[eid];
        }
        __syncthreads();
        for (int i = 0; i < c; i++) acc += wgt[i] * hs[(size_t)sidx[i] * DIM + t];
        __syncthreads();
    }
    h[(size_t)n * DIM + t] = fmaxf(acc, 0.f);
}

// ---------------- sort each node's 128 features ascending ----------------
__global__ __launch_bounds__(128) void sort_rows(const float* __restrict__ h2,
                                                 float* __restrict__ hsort,
                                                 float* __restrict__ maxval) {
    __shared__ float buf[128];
    int n = blockIdx.x, t = threadIdx.x;
    buf[t] = h2[(size_t)n * DIM + t];
    __syncthreads();
    for (int k = 2; k <= 128; k <<= 1) {
        for (int j = k >> 1; j > 0; j >>= 1) {
            int ixj = t ^ j;
            float a = buf[t], b = buf[ixj];
            __syncthreads();
            bool up = ((t & k) == 0);
            float mn = fminf(a, b), mx = fmaxf(a, b);
            buf[t] = up ? ((t < ixj) ? mn : mx) : ((t < ixj) ? mx : mn);
            __syncthreads();
        }
    }
    hsort[(size_t)n * DIM + t] = buf[t];
    if (t == 127) maxval[n] = buf[127];
}

// ---------------- per-graph top-k(32 of 200) + gather pooled rows ----------------
__global__ __launch_bounds__(256) void topk_pool(const float* __restrict__ maxval,
                                                 const float* __restrict__ hsort,
                                                 float* __restrict__ pooled) {
    __shared__ float v[256];
    __shared__ int id[256];
    int b = blockIdx.x, t = threadIdx.x;
    v[t] = (t < NPG) ? maxval[b * NPG + t] : -1e30f;
    id[t] = t;
    __syncthreads();
    for (int k = 2; k <= 256; k <<= 1) {
        for (int j = k >> 1; j > 0; j >>= 1) {
            int ixj = t ^ j;
            float va = v[t], vb = v[ixj];
            int ia = id[t], ib = id[ixj];
            __syncthreads();
            bool dirDesc = ((t & k) == 0);
            bool cmp = (va > vb) || (va == vb && ia < ib);  // mine-first in desc order
            bool takeMine = ((t < ixj) == (dirDesc == cmp));
            v[t] = takeMine ? va : vb;
            id[t] = takeMine ? ia : ib;
            __syncthreads();
        }
    }
    for (int i = t; i < KPOOL * DIM; i += 256) {
        int kk = i >> 7, d = i & 127;
        pooled[((size_t)b * KPOOL + kk) * DIM + d] = hsort[((size_t)b * NPG + id[kk]) * DIM + d];
    }
}

// ---------------- ft = pooled @ W3 ; sl = ft@al3 ; sr = ft@ar3 ----------------
__global__ __launch_bounds__(128) void ft_kernel(
    const float* __restrict__ pooled, const float* __restrict__ W3,
    const float* __restrict__ al3, const float* __restrict__ ar3,
    float* __restrict__ ft, float* __restrict__ sl, float* __restrict__ sr) {
    __shared__ float ps[KPOOL * DIM];
    __shared__ float r1[128], r2[128];
    int b = blockIdx.x, d = threadIdx.x;
    for (int i = d; i < KPOOL * DIM; i += 128) ps[i] = pooled[(size_t)b * KPOOL * DIM + i];
    __syncthreads();
    float acc = 0.f;
    for (int k = 0; k < KPOOL * DIM; k++) acc += ps[k] * W3[(size_t)k * DIM + d];
    ft[b * DIM + d] = acc;
    r1[d] = acc * al3[d];
    r2[d] = acc * ar3[d];
    __syncthreads();
    for (int s = 64; s > 0; s >>= 1) {
        if (d < s) { r1[d] += r1[d + s]; r2[d] += r2[d + s]; }
        __syncthreads();
    }
    if (d == 0) { sl[b] = r1[0]; sr[b] = r2[0]; }
}

// ---------------- final-graph GAT: softmax over fg_dst + aggregate ----------------
__global__ __launch_bounds__(128) void fg_kernel(
    const int* __restrict__ fg_src, const int* __restrict__ fg_dst,
    const float* __restrict__ sl, const float* __restrict__ sr,
    const float* __restrict__ ft, const float* __restrict__ b3,
    float* __restrict__ g) {
    __shared__ int list[EFE];
    __shared__ float wgt[EFE];
    __shared__ float red[128];
    __shared__ int cnt;
    int b = blockIdx.x, t = threadIdx.x;
    if (t == 0) cnt = 0;
    __syncthreads();
    for (int e = t; e < EFE; e += 128)
        if (fg_dst[e] == b) { int p = atomicAdd(&cnt, 1); list[p] = e; }
    __syncthreads();
    int deg = cnt;
    float srb = sr[b];
    float m = -1e30f;
    for (int j = t; j < deg; j += 128) {
        float s = sl[fg_src[list[j]]] + srb;
        s = s > 0.f ? s : 0.2f * s;
        m = fmaxf(m, s);
    }
    red[t] = m;
    __syncthreads();
    for (int s = 64; s > 0; s >>= 1) { if (t < s) red[t] = fmaxf(red[t], red[t + s]); __syncthreads(); }
    m = red[0];
    __syncthreads();
    float se = 0.f;
    for (int j = t; j < deg; j += 128) {
        float s = sl[fg_src[list[j]]] + srb;
        s = s > 0.f ? s : 0.2f * s;
        se += __expf(s - m);
    }
    red[t] = se;
    __syncthreads();
    for (int s = 64; s > 0; s >>= 1) { if (t < s) red[t] += red[t + s]; __syncthreads(); }
    float inv = (deg > 0) ? 1.f / red[0] : 0.f;
    __syncthreads();
    for (int j = t; j < deg; j += 128) {
        float s = sl[fg_src[list[j]]] + srb;
        s = s > 0.f ? s : 0.2f * s;
        wgt[j] = __expf(s - m) * inv;
    }
    __syncthreads();
    float acc = 0.f;
    for (int j = 0; j < deg; j++) acc += wgt[j] * ft[(size_t)fg_src[list[j]] * DIM + t];
    g[b * DIM + t] = fmaxf(acc + b3[t], 0.f);
}

// ---------------- g2 = relu(g @ Wl + bl) ----------------
__global__ __launch_bounds__(128) void gl_kernel(const float* __restrict__ g,
                                                 const float* __restrict__ Wl,
                                                 const float* __restrict__ bl,
                                                 float* __restrict__ g2) {
    __shared__ float gs[128];
    int b = blockIdx.x, d = threadIdx.x;
    gs[d] = g[b * DIM + d];
    __syncthreads();
    float acc = 0.f;
    for (int k = 0; k < 128; k++) acc += gs[k] * Wl[k * DIM + d];
    g2[b * DIM + d] = fmaxf(acc + bl[d], 0.f);
}

// ---------------- out = g2 @ Wc + bc  (B x 2, fp32) ----------------
__global__ __launch_bounds__(256) void out_kernel(const float* __restrict__ g2,
                                                  const float* __restrict__ Wc,
                                                  const float* __restrict__ bc,
                                                  float* __restrict__ out) {
    int i = threadIdx.x;  // 256 = 128*2
    int b = i >> 1, j = i & 1;
    float acc = bc[j];
    for (int k = 0; k < 128; k++) acc += g2[b * DIM + k] * Wc[k * 2 + j];
    out[b * 2 + j] = acc;
}

extern "C" void kernel_launch(void* const* d_in, const int* in_sizes, int n_in,
                              void* d_out, int out_size, void* d_ws, size_t ws_size,
                              hipStream_t stream) {
    const int* tokens_h = (const int*)d_in[0];
    const int* tokens_e = (const int*)d_in[1];
    const int* src = (const int*)d_in[2];
    const int* dst = (const int*)d_in[3];
    const int* fg_src = (const int*)d_in[4];
    const int* fg_dst = (const int*)d_in[5];
    const float* token_emb = (const float*)d_in[6];
    const float* e_token_emb = (const float*)d_in[7];
    const float* W_ni = (const float*)d_in[8];
    const float* W_nj = (const float*)d_in[9];
    const float* W_fij = (const float*)d_in[10];
    const float* W_node = (const float*)d_in[11];
    const float* attn_e = (const float*)d_in[12];
    const float* bias_e = (const float*)d_in[13];
    const float* Wf = (const float*)d_in[14];
    const float* bf_ = (const float*)d_in[15];
    const float* W3 = (const float*)d_in[16];
    const float* al3 = (const float*)d_in[17];
    const float* ar3 = (const float*)d_in[18];
    const float* b3 = (const float*)d_in[19];
    const float* Wl = (const float*)d_in[20];
    const float* bl = (const float*)d_in[21];
    const float* Wc = (const float*)d_in[22];
    const float* bc = (const float*)d_in[23];
    float* out = (float*)d_out;

    char* w = (char*)d_ws;
    auto alloc = [&](size_t b) -> char* {
        char* p = w;
        w += (b + 255) & ~(size_t)255;
        return p;
    };
    float* h = (float*)alloc((size_t)N_NODES * DIM * 4);
    float* fni = (float*)alloc((size_t)N_NODES * DIM * 4);
    float* fnj = (float*)alloc((size_t)N_NODES * DIM * 4);
    float* hs = (float*)alloc((size_t)N_NODES * DIM * 4);
    float* e = (float*)alloc((size_t)N_EDGES * DIM * 4);
    float* score = (float*)alloc((size_t)N_EDGES * 4);
    int* deg = (int*)alloc((size_t)N_NODES * 4);
    int* off = (int*)alloc((size_t)(N_NODES + 1) * 4);
    int* cursor = (int*)alloc((size_t)N_NODES * 4);
    int* csr = (int*)alloc((size_t)N_EDGES * 4);
    float* eftab = (float*)alloc(100 * DIM * 4);
    float* maxval = (float*)alloc((size_t)N_NODES * 4);
    float* pooled = (float*)alloc((size_t)BGR * KPOOL * DIM * 4);
    float* ft = (float*)alloc(BGR * DIM * 4);
    float* sl = (float*)alloc(BGR * 4);
    float* sr = (float*)alloc(BGR * 4);
    float* g = (float*)alloc(BGR * DIM * 4);
    float* g2 = (float*)alloc(BGR * DIM * 4);
    float* h2 = fni;    // reuse after last layer
    float* hsort = fnj; // reuse

    // CSR build (per call; ws is re-poisoned each launch)
    zero_deg<<<(N_NODES + 255) / 256, 256, 0, stream>>>(deg, N_NODES);
    count_deg<<<N_EDGES / 256, 256, 0, stream>>>(dst, deg, N_EDGES);
    scan_kernel<<<1, 1024, 0, stream>>>(deg, off, cursor, N_NODES);
    scatter_csr<<<N_EDGES / 256, 256, 0, stream>>>(dst, cursor, csr, N_EDGES);

    init_h<<<(N_NODES * DIM) / 256, 256, 0, stream>>>(tokens_h, token_emb, h);
    eftab_kernel<<<100, 128, 0, stream>>>(e_token_emb, W_fij, eftab);

    for (int l = 0; l < NLAYERS; l++) {
        node_gemm3<<<N_NODES / 64, 256, 0, stream>>>(
            h, W_ni + l * DIM * DIM, W_nj + l * DIM * DIM, W_node + l * DIM * DIM,
            fni, fnj, hs);
        if (l == 0) {
            edge0<<<(N_EDGES * 32) / 256, 256, 0, stream>>>(
                tokens_e, eftab, fni, fnj, src, dst, attn_e, bias_e, e, score);
        } else {
            edge_gemm<<<N_EDGES / 64, 256, 0, stream>>>(
                e, fni, fnj, src, dst, W_fij + l * DIM * DIM,
                attn_e + l * DIM, bias_e + l * DIM, score);
        }
        agg_kernel<<<N_NODES, 128, 0, stream>>>(off, csr, src, score, hs, h);
    }

    node_gemm1<<<N_NODES / 64, 256, 0, stream>>>(h, Wf, bf_, h2);
    sort_rows<<<N_NODES, 128, 0, stream>>>(h2, hsort, maxval);
    topk_pool<<<BGR, 256, 0, stream>>>(maxval, hsort, pooled);
    ft_kernel<<<BGR, 128, 0, stream>>>(pooled, W3, al3, ar3, ft, sl, sr);
    fg_kernel<<<BGR, 128, 0, stream>>>(fg_src, fg_dst, sl, sr, ft, b3, g);
    gl_kernel<<<BGR, 128, 0, stream>>>(g, Wl, bl, g2);
    out_kernel<<<1, 256, 0, stream>>>(g2, Wc, bc, out);
}

// Round 4
// 2321.070 us; speedup vs baseline: 1.2852x; 1.2852x over previous
//
#include <hip/hip_runtime.h>

#define N_NODES 25600
#define N_EDGES 409600
#define BGR 128
#define EFE 1024
#define DIM 128
#define NLAYERS 8
#define KPOOL 32
#define NPG 200

typedef unsigned short ushort_t;
typedef __attribute__((ext_vector_type(8))) short bf16x8;
typedef __attribute__((ext_vector_type(4))) float f32x4;

#define ET_S 136   // eTile LDS stride (bf16 elems), 272B row = 17*16B -> bank-spread + 16B aligned
#define WT_S 136   // w tile LDS stride (bf16)
#define ST_S 132   // fp32 staging stride

__device__ __forceinline__ ushort_t f2b(float f) {
    unsigned int u = __float_as_uint(f);
    unsigned int r = (u + 0x7fffu + ((u >> 16) & 1u)) >> 16;
    return (ushort_t)r;
}

// ---------------- W_fij -> transposed bf16 (Wt[l][n][k] = W[l][k][n]) ----------------
__global__ void wtprep(const float* __restrict__ W, ushort_t* __restrict__ Wt) {
    int idx = blockIdx.x * 256 + threadIdx.x;  // 8 * 16384
    int l = idx >> 14, rem = idx & 16383;
    int k = rem >> 7, n = rem & 127;           // lanes vary n fastest -> coalesced reads
    Wt[l * 16384 + n * 128 + k] = f2b(W[l * 16384 + k * 128 + n]);
}

// ---------------- zero deg ----------------
__global__ void zero_deg(int* __restrict__ deg, int n) {
    int i = blockIdx.x * 256 + threadIdx.x;
    if (i < n) deg[i] = 0;
}

// ---------------- CSR build ----------------
__global__ void count_deg(const int* __restrict__ dst, int* __restrict__ deg, int n) {
    int i = blockIdx.x * 256 + threadIdx.x;
    if (i < n) atomicAdd(&deg[dst[i]], 1);
}

__global__ __launch_bounds__(1024) void scan_kernel(const int* __restrict__ deg,
                                                    int* __restrict__ off,
                                                    int* __restrict__ cursor, int n) {
    __shared__ int buf[1024];
    __shared__ int carry;
    int t = threadIdx.x;
    if (t == 0) carry = 0;
    __syncthreads();
    for (int base = 0; base < n; base += 1024) {
        int v = (base + t < n) ? deg[base + t] : 0;
        buf[t] = v;
        __syncthreads();
        for (int s = 1; s < 1024; s <<= 1) {
            int x = (t >= s) ? buf[t - s] : 0;
            __syncthreads();
            buf[t] += x;
            __syncthreads();
        }
        int excl = buf[t] - v;
        if (base + t < n) { off[base + t] = carry + excl; cursor[base + t] = carry + excl; }
        __syncthreads();
        if (t == 1023) carry += buf[1023];
        __syncthreads();
    }
    if (t == 0) off[n] = carry;
}

__global__ void scatter_csr(const int* __restrict__ dst, int* __restrict__ cursor,
                            int* __restrict__ csr, int n) {
    int i = blockIdx.x * 256 + threadIdx.x;
    if (i < n) {
        int p = atomicAdd(&cursor[dst[i]], 1);
        csr[p] = i;
    }
}

// ---------------- init ----------------
__global__ void init_h(const int* __restrict__ tok, const float* __restrict__ emb,
                       float* __restrict__ h) {
    int i = blockIdx.x * 256 + threadIdx.x;
    int r = i >> 7, d = i & 127;
    float v = emb[tok[r] * DIM + d];
    h[i] = fmaxf(v, 0.f);
}

// eftab[t][d] = sum_k e_token_emb[t][k] * W_fij0[k][d]
__global__ __launch_bounds__(128) void eftab_kernel(const float* __restrict__ etab,
                                                    const float* __restrict__ W,
                                                    float* __restrict__ out) {
    int r = blockIdx.x, d = threadIdx.x;
    float acc = 0.f;
    for (int k = 0; k < DIM; k++)
        acc += etab[r * DIM + k] * W[k * DIM + d];
    out[r * DIM + d] = acc;
}

// pack 4 floats -> bf16x4 in uint2
__device__ __forceinline__ uint2 pack4(float4 v) {
    uint2 p;
    p.x = (unsigned int)f2b(v.x) | ((unsigned int)f2b(v.y) << 16);
    p.y = (unsigned int)f2b(v.z) | ((unsigned int)f2b(v.w) << 16);
    return p;
}

// ---------------- node GEMMs (unchanged from R3) ----------------
__global__ __launch_bounds__(256) void node_gemm3(
    const float* __restrict__ A,
    const float* __restrict__ W0, const float* __restrict__ W1,
    const float* __restrict__ W2,
    float* __restrict__ C0, float* __restrict__ C1, float* __restrict__ C2) {
    __shared__ float As[64 * 128];
    __shared__ uint2 Ws4[128 * 32];
    int tid = threadIdx.x;
    size_t row0 = (size_t)blockIdx.x * 64;
    const float4* Ag = (const float4*)(A + row0 * DIM);
    for (int f = tid; f < 64 * 32; f += 256) ((float4*)As)[f] = Ag[f];
    int cq = tid & 31, r0 = (tid >> 5) * 8;
    const float* Wlist[3] = {W0, W1, W2};
    float* Clist[3] = {C0, C1, C2};
    for (int m = 0; m < 3; m++) {
        __syncthreads();
        const float4* Wg = (const float4*)Wlist[m];
        for (int i = tid; i < 128 * 32; i += 256) Ws4[i] = pack4(Wg[i]);
        __syncthreads();
        float acc[8][4] = {};
        for (int k = 0; k < 128; k++) {
            uint2 wp = Ws4[k * 32 + cq];
            float w0 = __uint_as_float(wp.x << 16);
            float w1 = __uint_as_float(wp.x & 0xffff0000u);
            float w2 = __uint_as_float(wp.y << 16);
            float w3 = __uint_as_float(wp.y & 0xffff0000u);
#pragma unroll
            for (int i = 0; i < 8; i++) {
                float a = As[(r0 + i) * 128 + k];
                acc[i][0] += a * w0; acc[i][1] += a * w1;
                acc[i][2] += a * w2; acc[i][3] += a * w3;
            }
        }
        float* Cp = Clist[m];
#pragma unroll
        for (int i = 0; i < 8; i++) {
            *(float4*)&Cp[(row0 + r0 + i) * DIM + cq * 4] =
                make_float4(acc[i][0], acc[i][1], acc[i][2], acc[i][3]);
        }
    }
}

__global__ __launch_bounds__(256) void node_gemm1(
    const float* __restrict__ A, const float* __restrict__ W,
    const float* __restrict__ bias, float* __restrict__ C) {
    __shared__ float As[64 * 128];
    __shared__ uint2 Ws4[128 * 32];
    int tid = threadIdx.x;
    size_t row0 = (size_t)blockIdx.x * 64;
    const float4* Ag = (const float4*)(A + row0 * DIM);
    for (int f = tid; f < 64 * 32; f += 256) ((float4*)As)[f] = Ag[f];
    const float4* Wg = (const float4*)W;
    for (int i = tid; i < 128 * 32; i += 256) Ws4[i] = pack4(Wg[i]);
    __syncthreads();
    int cq = tid & 31, r0 = (tid >> 5) * 8, c0 = cq * 4;
    float acc[8][4] = {};
    for (int k = 0; k < 128; k++) {
        uint2 wp = Ws4[k * 32 + cq];
        float w0 = __uint_as_float(wp.x << 16);
        float w1 = __uint_as_float(wp.x & 0xffff0000u);
        float w2 = __uint_as_float(wp.y << 16);
        float w3 = __uint_as_float(wp.y & 0xffff0000u);
#pragma unroll
        for (int i = 0; i < 8; i++) {
            float a = As[(r0 + i) * 128 + k];
            acc[i][0] += a * w0; acc[i][1] += a * w1;
            acc[i][2] += a * w2; acc[i][3] += a * w3;
        }
    }
    float b0 = bias[c0], b1 = bias[c0 + 1], b2v = bias[c0 + 2], b3v = bias[c0 + 3];
#pragma unroll
    for (int i = 0; i < 8; i++) {
        *(float4*)&C[(row0 + r0 + i) * DIM + c0] =
            make_float4(fmaxf(acc[i][0] + b0, 0.f), fmaxf(acc[i][1] + b1, 0.f),
                        fmaxf(acc[i][2] + b2v, 0.f), fmaxf(acc[i][3] + b3v, 0.f));
    }
}

// ---------------- MFMA edge GEMM (layers 1..7): e(bf16) @ Wt(bf16) + epilogue ----------------
__global__ __launch_bounds__(256) void edge_gemm_mfma(
    ushort_t* __restrict__ e,                       // bf16 E x 128, in/out
    const float* __restrict__ fni, const float* __restrict__ fnj,
    const int* __restrict__ src, const int* __restrict__ dst,
    const ushort_t* __restrict__ Wt,                // bf16 [n][k] (pre-transposed)
    const float* __restrict__ attn, const float* __restrict__ bias,
    float* __restrict__ score) {
    __shared__ char smem[64 * ET_S * 2 + 128 * WT_S * 2];  // 17408 + 34816 = 52224 B
    ushort_t* eT = (ushort_t*)smem;                  // [64][ET_S]
    ushort_t* wT = (ushort_t*)(smem + 64 * ET_S * 2);// [128][WT_S]
    float* stg = (float*)(smem + 64 * ET_S * 2);     // [64][ST_S] fp32, reuses wT after K loop

    int tid = threadIdx.x;
    size_t e0 = (size_t)blockIdx.x * 64;

    // stage e tile: 64 rows x 128 bf16 = 1024 uint4
    {
        const uint4* eg = (const uint4*)(e + e0 * DIM);
        for (int idx = tid; idx < 1024; idx += 256) {
            int row = idx >> 4, ch = idx & 15;
            *(uint4*)(eT + row * ET_S + ch * 8) = eg[idx];
        }
    }
    // stage Wt: 128 rows x 128 bf16 = 2048 uint4
    {
        const uint4* wg = (const uint4*)Wt;
        for (int idx = tid; idx < 2048; idx += 256) {
            int row = idx >> 4, ch = idx & 15;
            *(uint4*)(wT + row * WT_S + ch * 8) = wg[idx];
        }
    }
    __syncthreads();

    int wv = tid >> 6, lane = tid & 63;
    int r = lane & 15, q = lane >> 4;
    f32x4 acc[8] = {};
    const ushort_t* aBase = eT + (16 * wv + r) * ET_S + q * 8;
    const ushort_t* bBase = wT + r * WT_S + q * 8;
#pragma unroll
    for (int kc = 0; kc < 4; kc++) {
        bf16x8 aF = *(const bf16x8*)(aBase + kc * 32);
#pragma unroll
        for (int nt = 0; nt < 8; nt++) {
            bf16x8 bF = *(const bf16x8*)(bBase + nt * 16 * WT_S + kc * 32);
            acc[nt] = __builtin_amdgcn_mfma_f32_16x16x32_bf16(aF, bF, acc[nt], 0, 0, 0);
        }
    }
    __syncthreads();  // done reading wT; reuse as fp32 staging

    // C/D layout: col = nt*16 + (lane&15), row = 16*wv + (lane>>4)*4 + reg
#pragma unroll
    for (int nt = 0; nt < 8; nt++) {
#pragma unroll
        for (int rg = 0; rg < 4; rg++) {
            int row = 16 * wv + q * 4 + rg;
            stg[row * ST_S + nt * 16 + r] = acc[nt][rg];
        }
    }
    __syncthreads();

    // epilogue: 4 threads per edge, 32 cols each
    int el = tid >> 2, qq = tid & 3;
    size_t eid = e0 + el;
    int sv = src[eid], dv = dst[eid];
    const float* nip = fni + (size_t)sv * DIM + qq * 32;
    const float* njp = fnj + (size_t)dv * DIM + qq * 32;
    const float* sp = stg + el * ST_S + qq * 32;
    float p = 0.f;
#pragma unroll
    for (int cc = 0; cc < 8; cc++) {
        float4 av = *(const float4*)(sp + cc * 4);
        float4 ni = *(const float4*)(nip + cc * 4);
        float4 nj = *(const float4*)(njp + cc * 4);
        int c = qq * 32 + cc * 4;
        float v0 = av.x + ni.x + nj.x + bias[c];
        float v1 = av.y + ni.y + nj.y + bias[c + 1];
        float v2 = av.z + ni.z + nj.z + bias[c + 2];
        float v3 = av.w + ni.w + nj.w + bias[c + 3];
        v0 = v0 > 0.f ? v0 : 0.01f * v0;
        v1 = v1 > 0.f ? v1 : 0.01f * v1;
        v2 = v2 > 0.f ? v2 : 0.01f * v2;
        v3 = v3 > 0.f ? v3 : 0.01f * v3;
        *(uint2*)(e + eid * DIM + c) = pack4(make_float4(v0, v1, v2, v3));
        p += v0 * attn[c] + v1 * attn[c + 1] + v2 * attn[c + 2] + v3 * attn[c + 3];
    }
    p += __shfl_xor(p, 1);
    p += __shfl_xor(p, 2);
    if (qq == 0) score[eid] = p;
}

// ---------------- layer-0 edge kernel (writes bf16 e) ----------------
__global__ __launch_bounds__(256) void edge0(
    const int* __restrict__ tokens_e, const float* __restrict__ eftab,
    const float* __restrict__ fni, const float* __restrict__ fnj,
    const int* __restrict__ src, const int* __restrict__ dst,
    const float* __restrict__ attn, const float* __restrict__ bias,
    ushort_t* __restrict__ e, float* __restrict__ score) {
    unsigned int gid = blockIdx.x * 256 + threadIdx.x;  // E*32 threads
    unsigned int eid = gid >> 5;
    int cq = gid & 31, c0 = cq * 4;
    int tok = tokens_e[eid];
    int sv = src[eid], dv = dst[eid];
    float4 t = *(const float4*)&eftab[tok * DIM + c0];
    float4 ni = *(const float4*)&fni[(size_t)sv * DIM + c0];
    float4 nj = *(const float4*)&fnj[(size_t)dv * DIM + c0];
    float v0 = t.x + ni.x + nj.x + bias[c0];
    float v1 = t.y + ni.y + nj.y + bias[c0 + 1];
    float v2 = t.z + ni.z + nj.z + bias[c0 + 2];
    float v3 = t.w + ni.w + nj.w + bias[c0 + 3];
    v0 = v0 > 0.f ? v0 : 0.01f * v0;
    v1 = v1 > 0.f ? v1 : 0.01f * v1;
    v2 = v2 > 0.f ? v2 : 0.01f * v2;
    v3 = v3 > 0.f ? v3 : 0.01f * v3;
    *(uint2*)(e + (size_t)eid * DIM + c0) = pack4(make_float4(v0, v1, v2, v3));
    float p = v0 * attn[c0] + v1 * attn[c0 + 1] + v2 * attn[c0 + 2] + v3 * attn[c0 + 3];
#pragma unroll
    for (int o = 1; o < 32; o <<= 1) p += __shfl_xor(p, o);
    if (cq == 0) score[eid] = p;
}

// ---------------- per-node softmax + weighted aggregation ----------------
__global__ __launch_bounds__(128) void agg_kernel(
    const int* __restrict__ off, const int* __restrict__ csr, const int* __restrict__ src,
    const float* __restrict__ score, const float* __restrict__ hs, float* __restrict__ h) {
    int n = blockIdx.x, t = threadIdx.x;
    int b0 = off[n], b1 = off[n + 1];
    int deg = b1 - b0;
    __shared__ float red[128];
    __shared__ float wgt[128];
    __shared__ int sidx[128];
    float m = -1e30f;
    for (int j = t; j < deg; j += 128) m = fmaxf(m, score[csr[b0 + j]]);
    red[t] = m;
    __syncthreads();
    for (int s = 64; s > 0; s >>= 1) { if (t < s) red[t] = fmaxf(red[t], red[t + s]); __syncthreads(); }
    m = red[0];
    __syncthreads();
    float se = 0.f;
    for (int j = t; j < deg; j += 128) se += __expf(score[csr[b0 + j]] - m);
    red[t] = se;
    __syncthreads();
    for (int s = 64; s > 0; s >>= 1) { if (t < s) red[t] += red[t + s]; __syncthreads(); }
    float inv = (deg > 0) ? 1.f / red[0] : 0.f;
    __syncthreads();
    float acc = 0.f;
    for (int base = 0; base < deg; base += 128) {
        int c = min(128, deg - base);
        if (t < c) {
            int eid = csr[b0 + base + t];
            wgt[t] = __expf(score[eid] - m) * inv;
            sidx[t] = src[eid];
        }
        __syncthreads();
        for (int i = 0; i < c; i++) acc += wgt[i] * hs[(size_t)sidx[i] * DIM + t];
        __syncthreads();
    }
    h[(size_t)n * DIM + t] = fmaxf(acc, 0.f);
}

// ---------------- sort each node's 128 features ascending ----------------
__global__ __launch_bounds__(128) void sort_rows(const float* __restrict__ h2,
                                                 float* __restrict__ hsort,
                                                 float* __restrict__ maxval) {
    __shared__ float buf[128];
    int n = blockIdx.x, t = threadIdx.x;
    buf[t] = h2[(size_t)n * DIM + t];
    __syncthreads();
    for (int k = 2; k <= 128; k <<= 1) {
        for (int j = k >> 1; j > 0; j >>= 1) {
            int ixj = t ^ j;
            float a = buf[t], b = buf[ixj];
            __syncthreads();
            bool up = ((t & k) == 0);
            float mn = fminf(a, b), mx = fmaxf(a, b);
            buf[t] = up ? ((t < ixj) ? mn : mx) : ((t < ixj) ? mx : mn);
            __syncthreads();
        }
    }
    hsort[(size_t)n * DIM + t] = buf[t];
    if (t == 127) maxval[n] = buf[127];
}

// ---------------- per-graph top-k + gather pooled rows ----------------
__global__ __launch_bounds__(256) void topk_pool(const float* __restrict__ maxval,
                                                 const float* __restrict__ hsort,
                                                 float* __restrict__ pooled) {
    __shared__ float v[256];
    __shared__ int id[256];
    int b = blockIdx.x, t = threadIdx.x;
    v[t] = (t < NPG) ? maxval[b * NPG + t] : -1e30f;
    id[t] = t;
    __syncthreads();
    for (int k = 2; k <= 256; k <<= 1) {
        for (int j = k >> 1; j > 0; j >>= 1) {
            int ixj = t ^ j;
            float va = v[t], vb = v[ixj];
            int ia = id[t], ib = id[ixj];
            __syncthreads();
            bool dirDesc = ((t & k) == 0);
            bool cmp = (va > vb) || (va == vb && ia < ib);
            bool takeMine = ((t < ixj) == (dirDesc == cmp));
            v[t] = takeMine ? va : vb;
            id[t] = takeMine ? ia : ib;
            __syncthreads();
        }
    }
    for (int i = t; i < KPOOL * DIM; i += 256) {
        int kk = i >> 7, d = i & 127;
        pooled[((size_t)b * KPOOL + kk) * DIM + d] = hsort[((size_t)b * NPG + id[kk]) * DIM + d];
    }
}

// ---------------- ft = pooled @ W3 ; sl = ft@al3 ; sr = ft@ar3 ----------------
__global__ __launch_bounds__(128) void ft_kernel(
    const float* __restrict__ pooled, const float* __restrict__ W3,
    const float* __restrict__ al3, const float* __restrict__ ar3,
    float* __restrict__ ft, float* __restrict__ sl, float* __restrict__ sr) {
    __shared__ float ps[KPOOL * DIM];
    __shared__ float r1[128], r2[128];
    int b = blockIdx.x, d = threadIdx.x;
    for (int i = d; i < KPOOL * DIM; i += 128) ps[i] = pooled[(size_t)b * KPOOL * DIM + i];
    __syncthreads();
    float acc = 0.f;
    for (int k = 0; k < KPOOL * DIM; k++) acc += ps[k] * W3[(size_t)k * DIM + d];
    ft[b * DIM + d] = acc;
    r1[d] = acc * al3[d];
    r2[d] = acc * ar3[d];
    __syncthreads();
    for (int s = 64; s > 0; s >>= 1) {
        if (d < s) { r1[d] += r1[d + s]; r2[d] += r2[d + s]; }
        __syncthreads();
    }
    if (d == 0) { sl[b] = r1[0]; sr[b] = r2[0]; }
}

// ---------------- final-graph GAT ----------------
__global__ __launch_bounds__(128) void fg_kernel(
    const int* __restrict__ fg_src, const int* __restrict__ fg_dst,
    const float* __restrict__ sl, const float* __restrict__ sr,
    const float* __restrict__ ft, const float* __restrict__ b3,
    float* __restrict__ g) {
    __shared__ int list[EFE];
    __shared__ float wgt[EFE];
    __shared__ float red[128];
    __shared__ int cnt;
    int b = blockIdx.x, t = threadIdx.x;
    if (t == 0) cnt = 0;
    __syncthreads();
    for (int e = t; e < EFE; e += 128)
        if (fg_dst[e] == b) { int p = atomicAdd(&cnt, 1); list[p] = e; }
    __syncthreads();
    int deg = cnt;
    float srb = sr[b];
    float m = -1e30f;
    for (int j = t; j < deg; j += 128) {
        float s = sl[fg_src[list[j]]] + srb;
        s = s > 0.f ? s : 0.2f * s;
        m = fmaxf(m, s);
    }
    red[t] = m;
    __syncthreads();
    for (int s = 64; s > 0; s >>= 1) { if (t < s) red[t] = fmaxf(red[t], red[t + s]); __syncthreads(); }
    m = red[0];
    __syncthreads();
    float se = 0.f;
    for (int j = t; j < deg; j += 128) {
        float s = sl[fg_src[list[j]]] + srb;
        s = s > 0.f ? s : 0.2f * s;
        se += __expf(s - m);
    }
    red[t] = se;
    __syncthreads();
    for (int s = 64; s > 0; s >>= 1) { if (t < s) red[t] += red[t + s]; __syncthreads(); }
    float inv = (deg > 0) ? 1.f / red[0] : 0.f;
    __syncthreads();
    for (int j = t; j < deg; j += 128) {
        float s = sl[fg_src[list[j]]] + srb;
        s = s > 0.f ? s : 0.2f * s;
        wgt[j] = __expf(s - m) * inv;
    }
    __syncthreads();
    float acc = 0.f;
    for (int j = 0; j < deg; j++) acc += wgt[j] * ft[(size_t)fg_src[list[j]] * DIM + t];
    g[b * DIM + t] = fmaxf(acc + b3[t], 0.f);
}

// ---------------- g2 = relu(g @ Wl + bl) ----------------
__global__ __launch_bounds__(128) void gl_kernel(const float* __restrict__ g,
                                                 const float* __restrict__ Wl,
                                                 const float* __restrict__ bl,
                                                 float* __restrict__ g2) {
    __shared__ float gs[128];
    int b = blockIdx.x, d = threadIdx.x;
    gs[d] = g[b * DIM + d];
    __syncthreads();
    float acc = 0.f;
    for (int k = 0; k < 128; k++) acc += gs[k] * Wl[k * DIM + d];
    g2[b * DIM + d] = fmaxf(acc + bl[d], 0.f);
}

// ---------------- out = g2 @ Wc + bc ----------------
__global__ __launch_bounds__(256) void out_kernel(const float* __restrict__ g2,
                                                  const float* __restrict__ Wc,
                                                  const float* __restrict__ bc,
                                                  float* __restrict__ out) {
    int i = threadIdx.x;
    int b = i >> 1, j = i & 1;
    float acc = bc[j];
    for (int k = 0; k < 128; k++) acc += g2[b * DIM + k] * Wc[k * 2 + j];
    out[b * 2 + j] = acc;
}

extern "C" void kernel_launch(void* const* d_in, const int* in_sizes, int n_in,
                              void* d_out, int out_size, void* d_ws, size_t ws_size,
                              hipStream_t stream) {
    const int* tokens_h = (const int*)d_in[0];
    const int* tokens_e = (const int*)d_in[1];
    const int* src = (const int*)d_in[2];
    const int* dst = (const int*)d_in[3];
    const int* fg_src = (const int*)d_in[4];
    const int* fg_dst = (const int*)d_in[5];
    const float* token_emb = (const float*)d_in[6];
    const float* e_token_emb = (const float*)d_in[7];
    const float* W_ni = (const float*)d_in[8];
    const float* W_nj = (const float*)d_in[9];
    const float* W_fij = (const float*)d_in[10];
    const float* W_node = (const float*)d_in[11];
    const float* attn_e = (const float*)d_in[12];
    const float* bias_e = (const float*)d_in[13];
    const float* Wf = (const float*)d_in[14];
    const float* bf_ = (const float*)d_in[15];
    const float* W3 = (const float*)d_in[16];
    const float* al3 = (const float*)d_in[17];
    const float* ar3 = (const float*)d_in[18];
    const float* b3 = (const float*)d_in[19];
    const float* Wl = (const float*)d_in[20];
    const float* bl = (const float*)d_in[21];
    const float* Wc = (const float*)d_in[22];
    const float* bc = (const float*)d_in[23];
    float* out = (float*)d_out;

    char* w = (char*)d_ws;
    auto alloc = [&](size_t b) -> char* {
        char* p = w;
        w += (b + 255) & ~(size_t)255;
        return p;
    };
    float* h = (float*)alloc((size_t)N_NODES * DIM * 4);
    float* fni = (float*)alloc((size_t)N_NODES * DIM * 4);
    float* fnj = (float*)alloc((size_t)N_NODES * DIM * 4);
    float* hs = (float*)alloc((size_t)N_NODES * DIM * 4);
    ushort_t* e = (ushort_t*)alloc((size_t)N_EDGES * DIM * 2);   // bf16 now
    float* score = (float*)alloc((size_t)N_EDGES * 4);
    int* deg = (int*)alloc((size_t)N_NODES * 4);
    int* off = (int*)alloc((size_t)(N_NODES + 1) * 4);
    int* cursor = (int*)alloc((size_t)N_NODES * 4);
    int* csr = (int*)alloc((size_t)N_EDGES * 4);
    float* eftab = (float*)alloc(100 * DIM * 4);
    float* maxval = (float*)alloc((size_t)N_NODES * 4);
    float* pooled = (float*)alloc((size_t)BGR * KPOOL * DIM * 4);
    float* ft = (float*)alloc(BGR * DIM * 4);
    float* sl = (float*)alloc(BGR * 4);
    float* sr = (float*)alloc(BGR * 4);
    float* g = (float*)alloc(BGR * DIM * 4);
    float* g2 = (float*)alloc(BGR * DIM * 4);
    ushort_t* Wt7 = (ushort_t*)alloc((size_t)NLAYERS * DIM * DIM * 2);
    float* h2 = fni;
    float* hsort = fnj;

    // prep: transposed bf16 W_fij
    wtprep<<<(NLAYERS * DIM * DIM) / 256, 256, 0, stream>>>(W_fij, Wt7);

    // CSR build
    zero_deg<<<(N_NODES + 255) / 256, 256, 0, stream>>>(deg, N_NODES);
    count_deg<<<N_EDGES / 256, 256, 0, stream>>>(dst, deg, N_EDGES);
    scan_kernel<<<1, 1024, 0, stream>>>(deg, off, cursor, N_NODES);
    scatter_csr<<<N_EDGES / 256, 256, 0, stream>>>(dst, cursor, csr, N_EDGES);

    init_h<<<(N_NODES * DIM) / 256, 256, 0, stream>>>(tokens_h, token_emb, h);
    eftab_kernel<<<100, 128, 0, stream>>>(e_token_emb, W_fij, eftab);

    for (int l = 0; l < NLAYERS; l++) {
        node_gemm3<<<N_NODES / 64, 256, 0, stream>>>(
            h, W_ni + l * DIM * DIM, W_nj + l * DIM * DIM, W_node + l * DIM * DIM,
            fni, fnj, hs);
        if (l == 0) {
            edge0<<<(N_EDGES * 32) / 256, 256, 0, stream>>>(
                tokens_e, eftab, fni, fnj, src, dst, attn_e, bias_e, e, score);
        } else {
            edge_gemm_mfma<<<N_EDGES / 64, 256, 0, stream>>>(
                e, fni, fnj, src, dst, Wt7 + l * DIM * DIM,
                attn_e + l * DIM, bias_e + l * DIM, score);
        }
        agg_kernel<<<N_NODES, 128, 0, stream>>>(off, csr, src, score, hs, h);
    }

    node_gemm1<<<N_NODES / 64, 256, 0, stream>>>(h, Wf, bf_, h2);
    sort_rows<<<N_NODES, 128, 0, stream>>>(h2, hsort, maxval);
    topk_pool<<<BGR, 256, 0, stream>>>(maxval, hsort, pooled);
    ft_kernel<<<BGR, 128, 0, stream>>>(pooled, W3, al3, ar3, ft, sl, sr);
    fg_kernel<<<BGR, 128, 0, stream>>>(fg_src, fg_dst, sl, sr, ft, b3, g);
    gl_kernel<<<BGR, 128, 0, stream>>>(g, Wl, bl, g2);
    out_kernel<<<1, 256, 0, stream>>>(g2, Wc, bc, out);
}